// Round 18
// baseline (147.223 us; speedup 1.0000x reference)
//
#include <hip/hip_runtime.h>

#define THREADS 256
#define NPH 4        // src phases (s>>14)
#define SUB 24       // slots per (node,phase); Poisson(4), P(>=24) ~ 1e-12
#define SEG (NPH*SUB)

typedef _Float16 f16;
typedef f16   f16x8 __attribute__((ext_vector_type(8)));
typedef float f32x4 __attribute__((ext_vector_type(4)));

__global__ void k_zero(unsigned* __restrict__ cnt4, int n4){
  int i = blockIdx.x*blockDim.x + threadIdx.x;   // over n4 int4s
  if(i < n4) ((int4*)cnt4)[i] = make_int4(0,0,0,0);
}

// one-pass CSR build into fixed per-(dst,srcphase) sub-segments.
// dst-range-partitioned (uniform short blocks -> blockIdx&7 ~ XCD).
__global__ void k_build1(const int* __restrict__ ei, unsigned* __restrict__ cnt4,
                         int* __restrict__ ssrc, int E, int M){
  const int grp = blockIdx.x & 7;
  const int nb  = blockIdx.x >> 3;
  const int lo  = grp * (M >> 3);
  const int hi  = (grp == 7) ? M : lo + (M >> 3);
  int e = nb*THREADS + threadIdx.x;
  if(e < E){
    int d = ei[E+e];
    if(d >= lo && d < hi){
      int s = ei[e];
      int ph = s >> 14;                       // 0..3 for s < 50000
      unsigned p = atomicAdd(&cnt4[d*NPH + ph], 1u);
      if(p < SUB) ssrc[(size_t)d*SEG + ph*SUB + p] = s;
    }
  }
}

__device__ __forceinline__ float deg_rsqrt(const unsigned* cnt4, int node){
  uint4 cc = ((const uint4*)cnt4)[node];
  return rsqrtf((float)(cc.x + cc.y + cc.z + cc.w + 1u));
}

// ---- MFMA GEMM layer1: BM=64, plain f16, f16 out scaled by rsqrt(deg+1) ----
template<int K, int N>
__global__ void k_gemm1(const float* __restrict__ A, const float* __restrict__ W,
                        const unsigned* __restrict__ cnt4, f16* __restrict__ Hh, int M){
  constexpr int BM = 64, BK = 32, BN = N;     // N=128
  constexpr int AST = 40;
  constexpr int NM = 4, NN = 2;
  constexpr int SKN = BK*BN/THREADS;          // 16
  __shared__ f16 Ah[BM*AST], Bh[BN*AST];

  const int tid  = threadIdx.x;
  const int row0 = blockIdx.x*BM;
  const int wc = tid>>6, l = tid&63;
  const int lr = l&15, lk = l>>4;

  const int sar = tid>>2, sak = (tid&3)*8;
  const long long garow = min(row0+sar, M-1);
  const int sc = tid & (BN-1), sk0 = (tid>>7)*SKN;

  f32x4 acc[NM][NN] = {};

  for(int k0 = 0; k0 < K; k0 += BK){
    float avals[8];
    #pragma unroll
    for(int q=0;q<2;q++){
      float4 v = *(const float4*)(A + garow*K + k0 + sak + q*4);
      avals[q*4+0]=v.x; avals[q*4+1]=v.y; avals[q*4+2]=v.z; avals[q*4+3]=v.w;
    }
    float bvals[SKN];
    #pragma unroll
    for(int i=0;i<SKN;i++) bvals[i] = W[(size_t)(k0+sk0+i)*N + sc];

    __syncthreads();

    {
      f16x8 hv;
      #pragma unroll
      for(int j=0;j<8;j++) hv[j] = (f16)avals[j];
      *(f16x8*)&Ah[sar*AST + sak] = hv;
    }
    #pragma unroll
    for(int s=0;s<SKN/8;s++){
      f16x8 hv;
      #pragma unroll
      for(int j=0;j<8;j++) hv[j] = (f16)bvals[s*8+j];
      *(f16x8*)&Bh[sc*AST + sk0 + s*8] = hv;
    }
    __syncthreads();

    f16x8 af[NM], bf[NN];
    #pragma unroll
    for(int m=0;m<NM;m++){
      int r = m*16 + lr;
      af[m] = *(const f16x8*)&Ah[r*AST + lk*8];
    }
    #pragma unroll
    for(int n=0;n<NN;n++){
      int c = wc*32 + n*16 + lr;
      bf[n] = *(const f16x8*)&Bh[c*AST + lk*8];
    }
    #pragma unroll
    for(int m=0;m<NM;m++)
      #pragma unroll
      for(int n=0;n<NN;n++)
        acc[m][n] = __builtin_amdgcn_mfma_f32_16x16x32_f16(af[m], bf[n], acc[m][n], 0,0,0);
  }

  #pragma unroll
  for(int m=0;m<NM;m++){
    int grb = row0 + m*16 + lk*4;
    #pragma unroll
    for(int reg=0;reg<4;reg++){
      int gr = grb + reg;
      if(gr < M){
        float dv = deg_rsqrt(cnt4, gr);
        #pragma unroll
        for(int n=0;n<NN;n++){
          int gc = wc*32 + n*16 + lr;
          Hh[(size_t)gr*N + gc] = (f16)(acc[m][n][reg] * dv);
        }
      }
    }
  }
}

// ---- MFMA GEMM layer2: BM=64, plain f16 A and W, f16 out scaled ----
template<int K, int N>
__global__ void k_gemm_mfma_f16a(const f16* __restrict__ A, const float* __restrict__ W,
                                 const unsigned* __restrict__ cnt4, f16* __restrict__ Hh, int M){
  constexpr int BM = 64, BK = 32, BN = N;     // N=64
  constexpr int AST = 40;
  constexpr int NM = 4;
  constexpr int SKN = BK*BN/THREADS;          // 8
  __shared__ f16 Ah[BM*AST], Bh[BN*AST];

  const int tid  = threadIdx.x;
  const int row0 = blockIdx.x*BM;
  const int wc = tid>>6, l = tid&63;
  const int lr = l&15, lk = l>>4;

  const int sar = tid>>2, sak = (tid&3)*8;
  const long long garow = min(row0+sar, M-1);
  const int sc = tid & (BN-1), sk0 = (tid>>6)*SKN;

  f32x4 acc[NM] = {};

  for(int k0 = 0; k0 < K; k0 += BK){
    f16x8 av = *(const f16x8*)(A + garow*K + k0 + sak);
    float bvals[SKN];
    #pragma unroll
    for(int i=0;i<SKN;i++) bvals[i] = W[(size_t)(k0+sk0+i)*N + sc];

    __syncthreads();

    *(f16x8*)&Ah[sar*AST + sak] = av;
    {
      f16x8 hv;
      #pragma unroll
      for(int j=0;j<8;j++) hv[j] = (f16)bvals[j];
      *(f16x8*)&Bh[sc*AST + sk0] = hv;
    }
    __syncthreads();

    f16x8 af[NM], bf;
    #pragma unroll
    for(int m=0;m<NM;m++){
      int r = m*16 + lr;
      af[m] = *(const f16x8*)&Ah[r*AST + lk*8];
    }
    {
      int c = wc*16 + lr;
      bf = *(const f16x8*)&Bh[c*AST + lk*8];
    }
    #pragma unroll
    for(int m=0;m<NM;m++)
      acc[m] = __builtin_amdgcn_mfma_f32_16x16x32_f16(af[m], bf, acc[m], 0,0,0);
  }

  #pragma unroll
  for(int m=0;m<NM;m++){
    int grb = row0 + m*16 + lk*4;
    #pragma unroll
    for(int reg=0;reg<4;reg++){
      int gr = grb + reg;
      if(gr < M){
        float dv = deg_rsqrt(cnt4, gr);
        int gc = wc*16 + lr;
        Hh[(size_t)gr*N + gc] = (f16)(acc[m][reg] * dv);
      }
    }
  }
}

// gather layer1: wave per node; 16 lanes x f16x8 cover the 128-col row; each
// wave-instruction fetches FOUR edges' rows. Src-phased: loop the 4 sub-segs
// so concurrent waves touch one ~4MB src slice of g at a time (L2-resident).
__global__ void k_gather_l1(const unsigned* __restrict__ cnt4, const int* __restrict__ ssrc,
                            const f16* __restrict__ g,
                            const float* __restrict__ bias, f16* __restrict__ outh, int M){
  const int w = (blockIdx.x*blockDim.x + threadIdx.x) >> 6;
  const int l = threadIdx.x & 63;
  if(w >= M) return;
  const int q = l>>4, c = l&15;
  const f16x8* g8 = (const f16x8*)g;        // row stride = 16 f16x8
  float acc[8] = {0.f,0.f,0.f,0.f,0.f,0.f,0.f,0.f};
  const uint4 cc = ((const uint4*)cnt4)[w];
  const unsigned nep[NPH] = {min(cc.x,(unsigned)SUB), min(cc.y,(unsigned)SUB),
                             min(cc.z,(unsigned)SUB), min(cc.w,(unsigned)SUB)};
  #pragma unroll
  for(int ph=0; ph<NPH; ph++){
    const int ne = (int)nep[ph];
    int it = ne >> 2;
    int i = w*SEG + ph*SUB + q;
    while(it >= 2){
      int s0 = ssrc[i], s1 = ssrc[i+4];
      f16x8 v0 = g8[(size_t)s0*16 + c];
      f16x8 v1 = g8[(size_t)s1*16 + c];
      #pragma unroll
      for(int j=0;j<8;j++) acc[j] += (float)v0[j] + (float)v1[j];
      i += 8; it -= 2;
    }
    if(it){
      int s = ssrc[i];
      f16x8 v = g8[(size_t)s*16 + c];
      #pragma unroll
      for(int j=0;j<8;j++) acc[j] += (float)v[j];
      i += 4;
    }
    if(q < (ne & 3)){
      int s = ssrc[i];
      f16x8 v = g8[(size_t)s*16 + c];
      #pragma unroll
      for(int j=0;j<8;j++) acc[j] += (float)v[j];
    }
  }
  if(q == 0){                                // self-loop (already *dinv[w])
    f16x8 v = g8[(size_t)w*16 + c];
    #pragma unroll
    for(int j=0;j<8;j++) acc[j] += (float)v[j];
  }
  #pragma unroll
  for(int j=0;j<8;j++){
    acc[j] += __shfl_xor(acc[j], 16);
    acc[j] += __shfl_xor(acc[j], 32);
  }
  if(q == 0){
    const float dw = rsqrtf((float)(cc.x + cc.y + cc.z + cc.w + 1u));
    float4 b0 = ((const float4*)bias)[c*2];
    float4 b1 = ((const float4*)bias)[c*2+1];
    f16x8 o;
    o[0] = (f16)fmaxf(fmaf(acc[0], dw, b0.x), 0.f);
    o[1] = (f16)fmaxf(fmaf(acc[1], dw, b0.y), 0.f);
    o[2] = (f16)fmaxf(fmaf(acc[2], dw, b0.z), 0.f);
    o[3] = (f16)fmaxf(fmaf(acc[3], dw, b0.w), 0.f);
    o[4] = (f16)fmaxf(fmaf(acc[4], dw, b1.x), 0.f);
    o[5] = (f16)fmaxf(fmaf(acc[5], dw, b1.y), 0.f);
    o[6] = (f16)fmaxf(fmaf(acc[6], dw, b1.z), 0.f);
    o[7] = (f16)fmaxf(fmaf(acc[7], dw, b1.w), 0.f);
    ((f16x8*)outh)[(size_t)w*16 + c] = o;
  }
}

// gather layer2: wave per node; 8 lanes x f16x8 cover the 64-col row -> EIGHT
// edges per wave-instruction. Src-phased (2.1MB slices); f32 output.
__global__ void k_gather_l2(const unsigned* __restrict__ cnt4, const int* __restrict__ ssrc,
                            const f16* __restrict__ g,
                            const float* __restrict__ bias, float* __restrict__ out, int M){
  const int w = (blockIdx.x*blockDim.x + threadIdx.x) >> 6;
  const int l = threadIdx.x & 63;
  if(w >= M) return;
  const int grp = l>>3, c = l&7;
  const f16x8* g8 = (const f16x8*)g;        // row stride = 8 f16x8
  float acc[8] = {0.f,0.f,0.f,0.f,0.f,0.f,0.f,0.f};
  const uint4 cc = ((const uint4*)cnt4)[w];
  const unsigned nep[NPH] = {min(cc.x,(unsigned)SUB), min(cc.y,(unsigned)SUB),
                             min(cc.z,(unsigned)SUB), min(cc.w,(unsigned)SUB)};
  #pragma unroll
  for(int ph=0; ph<NPH; ph++){
    const int ne = (int)nep[ph];
    int it = ne >> 3;
    int i = w*SEG + ph*SUB + grp;
    while(it){
      int s = ssrc[i];
      f16x8 v = g8[(size_t)s*8 + c];
      #pragma unroll
      for(int j=0;j<8;j++) acc[j] += (float)v[j];
      i += 8; --it;
    }
    if(grp < (ne & 7)){
      int s = ssrc[i];
      f16x8 v = g8[(size_t)s*8 + c];
      #pragma unroll
      for(int j=0;j<8;j++) acc[j] += (float)v[j];
    }
  }
  if(grp == 0){                              // self-loop (already *dinv[w])
    f16x8 v = g8[(size_t)w*8 + c];
    #pragma unroll
    for(int j=0;j<8;j++) acc[j] += (float)v[j];
  }
  #pragma unroll
  for(int j=0;j<8;j++){
    acc[j] += __shfl_xor(acc[j], 8);
    acc[j] += __shfl_xor(acc[j], 16);
    acc[j] += __shfl_xor(acc[j], 32);
  }
  if(grp == 0){
    const float dw = rsqrtf((float)(cc.x + cc.y + cc.z + cc.w + 1u));
    float4 b0 = ((const float4*)bias)[c*2];
    float4 b1 = ((const float4*)bias)[c*2+1];
    float4 o0, o1;
    o0.x = fmaf(acc[0], dw, b0.x);
    o0.y = fmaf(acc[1], dw, b0.y);
    o0.z = fmaf(acc[2], dw, b0.z);
    o0.w = fmaf(acc[3], dw, b0.w);
    o1.x = fmaf(acc[4], dw, b1.x);
    o1.y = fmaf(acc[5], dw, b1.y);
    o1.z = fmaf(acc[6], dw, b1.z);
    o1.w = fmaf(acc[7], dw, b1.w);
    ((float4*)out)[(size_t)w*16 + c*2]     = o0;
    ((float4*)out)[(size_t)w*16 + c*2 + 1] = o1;
  }
}

extern "C" void kernel_launch(void* const* d_in, const int* in_sizes, int n_in,
                              void* d_out, int out_size, void* d_ws, size_t ws_size,
                              hipStream_t stream){
  const float* feat = (const float*)d_in[0];
  const int*   ei   = (const int*)d_in[1];
  const float* W1   = (const float*)d_in[2];
  const float* b1   = (const float*)d_in[3];
  const float* W2   = (const float*)d_in[4];
  const float* b2   = (const float*)d_in[5];
  float* out = (float*)d_out;

  const int M = in_sizes[0] / 256;   // 50000 nodes
  const int E = in_sizes[1] / 2;     // 800000 edges

  float* ws = (float*)d_ws;
  unsigned* cnt4 = (unsigned*)ws;                  // M*4 u32 (800KB)
  int*      ssrc = (int*)(ws + 204800);            // M*SEG = 4.8M ints
  f16*      h1h  = (f16*)(ws + 5004800);           // M*128 f16
  f16*      o1h  = (f16*)(ws + 8204800);           // M*128 f16
  f16*      h2h  = h1h;                            // reuse (dead after gather1)

  const int nbE = (E + THREADS-1)/THREADS;
  const int gemmBlocks = (M + 63)/64;              // 782
  const int n4 = M;                                // M int4s = M*4 u32

  k_zero<<<(n4 + THREADS-1)/THREADS, THREADS, 0, stream>>>(cnt4, n4);
  k_build1<<<nbE*8, THREADS, 0, stream>>>(ei, cnt4, ssrc, E, M);

  k_gemm1<256,128><<<gemmBlocks, THREADS, 0, stream>>>(feat, W1, cnt4, h1h, M);
  k_gather_l1<<<(M*64 + THREADS-1)/THREADS, THREADS, 0, stream>>>(cnt4, ssrc, h1h, b1, o1h, M);

  k_gemm_mfma_f16a<128,64><<<gemmBlocks, THREADS, 0, stream>>>(o1h, W2, cnt4, h2h, M);
  k_gather_l2<<<(M*64 + THREADS-1)/THREADS, THREADS, 0, stream>>>(cnt4, ssrc, h2h, b2, out, M);
}

// Round 19
// 129.855 us; speedup vs baseline: 1.1337x; 1.1337x over previous
//
#include <hip/hip_runtime.h>

#define THREADS 256
#define SEG 96   // fixed slots per node; Poisson(16) max-deg over 50K << 96

typedef _Float16 f16;
typedef f16   f16x8 __attribute__((ext_vector_type(8)));
typedef float f32x4 __attribute__((ext_vector_type(4)));

__global__ void k_zero(unsigned* __restrict__ cnt, int n4){
  int i = blockIdx.x*blockDim.x + threadIdx.x;   // over n4 int4s
  if(i < n4) ((int4*)cnt)[i] = make_int4(0,0,0,0);
}

// ---- fused: CSR build (blocks [0,buildBlocks), dispatched FIRST -> clean
// round-robin XCD affinity for the dst-partitioned atomic writes) + layer-1
// MFMA GEMM (blocks above, UNSCALED f16 out; overlaps build's tail) ----
template<int K, int N>
__global__ void k_build_gemm1(const int* __restrict__ ei, unsigned* __restrict__ cnt,
                              int* __restrict__ ssrc, int E, int M,
                              const float* __restrict__ A, const float* __restrict__ W,
                              f16* __restrict__ Hh, int buildBlocks){
  constexpr int BM = 64, BK = 32, BN = N;     // N=128
  constexpr int AST = 40;
  constexpr int NM = 4, NN = 2;
  constexpr int SKN = BK*BN/THREADS;          // 16
  __shared__ f16 Ah[BM*AST], Bh[BN*AST];

  if((int)blockIdx.x < buildBlocks){
    // ---- build path: dst-range-partitioned, one XCD owns each ssrc window ----
    const int grp = blockIdx.x & 7;
    const int nb  = blockIdx.x >> 3;
    const int lo  = grp * (M >> 3);
    const int hi  = (grp == 7) ? M : lo + (M >> 3);
    int e = nb*THREADS + threadIdx.x;
    if(e < E){
      int d = ei[E+e];
      if(d >= lo && d < hi){
        int s = ei[e];
        unsigned p = atomicAdd(&cnt[d], 1u);
        if(p < SEG) ssrc[(size_t)d*SEG + p] = s;
      }
    }
    return;
  }

  // ---- gemm1 path (unscaled output; dinv applied per-edge in gather) ----
  const int bx   = (int)blockIdx.x - buildBlocks;
  const int tid  = threadIdx.x;
  const int row0 = bx*BM;
  const int wc = tid>>6, l = tid&63;
  const int lr = l&15, lk = l>>4;

  const int sar = tid>>2, sak = (tid&3)*8;
  const long long garow = min(row0+sar, M-1);
  const int sc = tid & (BN-1), sk0 = (tid>>7)*SKN;

  f32x4 acc[NM][NN] = {};

  for(int k0 = 0; k0 < K; k0 += BK){
    float avals[8];
    #pragma unroll
    for(int q=0;q<2;q++){
      float4 v = *(const float4*)(A + garow*K + k0 + sak + q*4);
      avals[q*4+0]=v.x; avals[q*4+1]=v.y; avals[q*4+2]=v.z; avals[q*4+3]=v.w;
    }
    float bvals[SKN];
    #pragma unroll
    for(int i=0;i<SKN;i++) bvals[i] = W[(size_t)(k0+sk0+i)*N + sc];

    __syncthreads();

    {
      f16x8 hv;
      #pragma unroll
      for(int j=0;j<8;j++) hv[j] = (f16)avals[j];
      *(f16x8*)&Ah[sar*AST + sak] = hv;
    }
    #pragma unroll
    for(int s=0;s<SKN/8;s++){
      f16x8 hv;
      #pragma unroll
      for(int j=0;j<8;j++) hv[j] = (f16)bvals[s*8+j];
      *(f16x8*)&Bh[sc*AST + sk0 + s*8] = hv;
    }
    __syncthreads();

    f16x8 af[NM], bf[NN];
    #pragma unroll
    for(int m=0;m<NM;m++){
      int r = m*16 + lr;
      af[m] = *(const f16x8*)&Ah[r*AST + lk*8];
    }
    #pragma unroll
    for(int n=0;n<NN;n++){
      int c = wc*32 + n*16 + lr;
      bf[n] = *(const f16x8*)&Bh[c*AST + lk*8];
    }
    #pragma unroll
    for(int m=0;m<NM;m++)
      #pragma unroll
      for(int n=0;n<NN;n++)
        acc[m][n] = __builtin_amdgcn_mfma_f32_16x16x32_f16(af[m], bf[n], acc[m][n], 0,0,0);
  }

  #pragma unroll
  for(int m=0;m<NM;m++){
    int grb = row0 + m*16 + lk*4;
    #pragma unroll
    for(int reg=0;reg<4;reg++){
      int gr = grb + reg;
      if(gr < M){
        #pragma unroll
        for(int n=0;n<NN;n++){
          int gc = wc*32 + n*16 + lr;
          Hh[(size_t)gr*N + gc] = (f16)(acc[m][n][reg]);   // unscaled
        }
      }
    }
  }
}

// ---- MFMA GEMM layer2: BM=64, plain f16 A and W, f16 out scaled by rsqrt(cnt+1) ----
template<int K, int N>
__global__ void k_gemm_mfma_f16a(const f16* __restrict__ A, const float* __restrict__ W,
                                 const unsigned* __restrict__ cnt, f16* __restrict__ Hh, int M){
  constexpr int BM = 64, BK = 32, BN = N;     // N=64
  constexpr int AST = 40;
  constexpr int NM = 4;
  constexpr int SKN = BK*BN/THREADS;          // 8
  __shared__ f16 Ah[BM*AST], Bh[BN*AST];

  const int tid  = threadIdx.x;
  const int row0 = blockIdx.x*BM;
  const int wc = tid>>6, l = tid&63;
  const int lr = l&15, lk = l>>4;

  const int sar = tid>>2, sak = (tid&3)*8;
  const long long garow = min(row0+sar, M-1);
  const int sc = tid & (BN-1), sk0 = (tid>>6)*SKN;

  f32x4 acc[NM] = {};

  for(int k0 = 0; k0 < K; k0 += BK){
    f16x8 av = *(const f16x8*)(A + garow*K + k0 + sak);
    float bvals[SKN];
    #pragma unroll
    for(int i=0;i<SKN;i++) bvals[i] = W[(size_t)(k0+sk0+i)*N + sc];

    __syncthreads();

    *(f16x8*)&Ah[sar*AST + sak] = av;
    {
      f16x8 hv;
      #pragma unroll
      for(int j=0;j<8;j++) hv[j] = (f16)bvals[j];
      *(f16x8*)&Bh[sc*AST + sk0] = hv;
    }
    __syncthreads();

    f16x8 af[NM], bf;
    #pragma unroll
    for(int m=0;m<NM;m++){
      int r = m*16 + lr;
      af[m] = *(const f16x8*)&Ah[r*AST + lk*8];
    }
    {
      int c = wc*16 + lr;
      bf = *(const f16x8*)&Bh[c*AST + lk*8];
    }
    #pragma unroll
    for(int m=0;m<NM;m++)
      acc[m] = __builtin_amdgcn_mfma_f32_16x16x32_f16(af[m], bf, acc[m], 0,0,0);
  }

  #pragma unroll
  for(int m=0;m<NM;m++){
    int grb = row0 + m*16 + lk*4;
    #pragma unroll
    for(int reg=0;reg<4;reg++){
      int gr = grb + reg;
      if(gr < M){
        float dv = rsqrtf((float)(cnt[gr] + 1u));
        int gc = wc*16 + lr;
        Hh[(size_t)gr*N + gc] = (f16)(acc[m][reg] * dv);
      }
    }
  }
}

// gather layer1: wave per node; 16 lanes x f16x8 cover the 128-col row; each
// wave-instruction fetches FOUR edges' rows; 2-deep unroll. h1 UNSCALED ->
// per-edge fma with rsqrt(cnt[s]+1); epilogue *dinv[w]+bias, relu, f16.
__global__ void k_gather_l1(const unsigned* __restrict__ cnt, const int* __restrict__ ssrc,
                            const f16* __restrict__ g,
                            const float* __restrict__ bias, f16* __restrict__ outh, int M){
  const int w = (blockIdx.x*blockDim.x + threadIdx.x) >> 6;
  const int l = threadIdx.x & 63;
  if(w >= M) return;
  const int q = l>>4, c = l&15;
  const f16x8* g8 = (const f16x8*)g;        // row stride = 16 f16x8
  float acc[8] = {0.f,0.f,0.f,0.f,0.f,0.f,0.f,0.f};
  const int ne = min((int)cnt[w], SEG);
  int it = ne >> 2;
  int i = w*SEG + q;
  while(it >= 2){
    int s0 = ssrc[i], s1 = ssrc[i+4];
    float d0 = rsqrtf((float)(cnt[s0] + 1u));
    float d1 = rsqrtf((float)(cnt[s1] + 1u));
    f16x8 v0 = g8[(size_t)s0*16 + c];
    f16x8 v1 = g8[(size_t)s1*16 + c];
    #pragma unroll
    for(int j=0;j<8;j++){
      acc[j] = fmaf((float)v0[j], d0, acc[j]);
      acc[j] = fmaf((float)v1[j], d1, acc[j]);
    }
    i += 8; it -= 2;
  }
  if(it){
    int s = ssrc[i];
    float ds = rsqrtf((float)(cnt[s] + 1u));
    f16x8 v = g8[(size_t)s*16 + c];
    #pragma unroll
    for(int j=0;j<8;j++) acc[j] = fmaf((float)v[j], ds, acc[j]);
    i += 4;
  }
  if(q < (ne & 3)){
    int s = ssrc[i];
    float ds = rsqrtf((float)(cnt[s] + 1u));
    f16x8 v = g8[(size_t)s*16 + c];
    #pragma unroll
    for(int j=0;j<8;j++) acc[j] = fmaf((float)v[j], ds, acc[j]);
  }
  const float dw = rsqrtf((float)(cnt[w] + 1u));
  if(q == 0){                                // self-loop term
    f16x8 v = g8[(size_t)w*16 + c];
    #pragma unroll
    for(int j=0;j<8;j++) acc[j] = fmaf((float)v[j], dw, acc[j]);
  }
  #pragma unroll
  for(int j=0;j<8;j++){
    acc[j] += __shfl_xor(acc[j], 16);
    acc[j] += __shfl_xor(acc[j], 32);
  }
  if(q == 0){
    float4 b0 = ((const float4*)bias)[c*2];
    float4 b1 = ((const float4*)bias)[c*2+1];
    f16x8 o;
    o[0] = (f16)fmaxf(fmaf(acc[0], dw, b0.x), 0.f);
    o[1] = (f16)fmaxf(fmaf(acc[1], dw, b0.y), 0.f);
    o[2] = (f16)fmaxf(fmaf(acc[2], dw, b0.z), 0.f);
    o[3] = (f16)fmaxf(fmaf(acc[3], dw, b0.w), 0.f);
    o[4] = (f16)fmaxf(fmaf(acc[4], dw, b1.x), 0.f);
    o[5] = (f16)fmaxf(fmaf(acc[5], dw, b1.y), 0.f);
    o[6] = (f16)fmaxf(fmaf(acc[6], dw, b1.z), 0.f);
    o[7] = (f16)fmaxf(fmaf(acc[7], dw, b1.w), 0.f);
    ((f16x8*)outh)[(size_t)w*16 + c] = o;
  }
}

// gather layer2: wave per node; 8 lanes x f16x8 cover the 64-col row -> EIGHT
// edges per wave-instruction; 2-deep unroll. g (h2h) pre-scaled; f32 output.
__global__ void k_gather_l2(const unsigned* __restrict__ cnt, const int* __restrict__ ssrc,
                            const f16* __restrict__ g,
                            const float* __restrict__ bias, float* __restrict__ out, int M){
  const int w = (blockIdx.x*blockDim.x + threadIdx.x) >> 6;
  const int l = threadIdx.x & 63;
  if(w >= M) return;
  const int grp = l>>3, c = l&7;
  const f16x8* g8 = (const f16x8*)g;        // row stride = 8 f16x8
  float acc[8] = {0.f,0.f,0.f,0.f,0.f,0.f,0.f,0.f};
  const int ne = min((int)cnt[w], SEG);
  int it = ne >> 3;
  int i = w*SEG + grp;
  while(it >= 2){
    int s0 = ssrc[i], s1 = ssrc[i+8];
    f16x8 v0 = g8[(size_t)s0*8 + c];
    f16x8 v1 = g8[(size_t)s1*8 + c];
    #pragma unroll
    for(int j=0;j<8;j++) acc[j] += (float)v0[j] + (float)v1[j];
    i += 16; it -= 2;
  }
  if(it){
    int s = ssrc[i];
    f16x8 v = g8[(size_t)s*8 + c];
    #pragma unroll
    for(int j=0;j<8;j++) acc[j] += (float)v[j];
    i += 8;
  }
  if(grp < (ne & 7)){
    int s = ssrc[i];
    f16x8 v = g8[(size_t)s*8 + c];
    #pragma unroll
    for(int j=0;j<8;j++) acc[j] += (float)v[j];
  }
  if(grp == 0){                              // self-loop (already *dinv[w])
    f16x8 v = g8[(size_t)w*8 + c];
    #pragma unroll
    for(int j=0;j<8;j++) acc[j] += (float)v[j];
  }
  #pragma unroll
  for(int j=0;j<8;j++){
    acc[j] += __shfl_xor(acc[j], 8);
    acc[j] += __shfl_xor(acc[j], 16);
    acc[j] += __shfl_xor(acc[j], 32);
  }
  if(grp == 0){
    const float dw = rsqrtf((float)(cnt[w] + 1u));
    float4 b0 = ((const float4*)bias)[c*2];
    float4 b1 = ((const float4*)bias)[c*2+1];
    float4 o0, o1;
    o0.x = fmaf(acc[0], dw, b0.x);
    o0.y = fmaf(acc[1], dw, b0.y);
    o0.z = fmaf(acc[2], dw, b0.z);
    o0.w = fmaf(acc[3], dw, b0.w);
    o1.x = fmaf(acc[4], dw, b1.x);
    o1.y = fmaf(acc[5], dw, b1.y);
    o1.z = fmaf(acc[6], dw, b1.z);
    o1.w = fmaf(acc[7], dw, b1.w);
    ((float4*)out)[(size_t)w*16 + c*2]     = o0;
    ((float4*)out)[(size_t)w*16 + c*2 + 1] = o1;
  }
}

extern "C" void kernel_launch(void* const* d_in, const int* in_sizes, int n_in,
                              void* d_out, int out_size, void* d_ws, size_t ws_size,
                              hipStream_t stream){
  const float* feat = (const float*)d_in[0];
  const int*   ei   = (const int*)d_in[1];
  const float* W1   = (const float*)d_in[2];
  const float* b1   = (const float*)d_in[3];
  const float* W2   = (const float*)d_in[4];
  const float* b2   = (const float*)d_in[5];
  float* out = (float*)d_out;

  const int M = in_sizes[0] / 256;   // 50000 nodes
  const int E = in_sizes[1] / 2;     // 800000 edges

  float* ws = (float*)d_ws;
  unsigned* cnt  = (unsigned*)ws;                  // 50176 u32
  int*      ssrc = (int*)(ws + 51200);             // M*SEG = 4.8M ints
  f16*      h1h  = (f16*)(ws + 5000000);           // M*128 f16
  f16*      o1h  = (f16*)(ws + 8400000);           // M*128 f16
  f16*      h2h  = h1h;                            // reuse (dead after gather1)

  const int nbE = (E + THREADS-1)/THREADS;         // 3125
  const int buildBlocks = nbE*8;                   // 25000
  const int gemmBlocks = (M + 63)/64;              // 782
  const int n4 = (M + 3)/4;

  k_zero<<<(n4 + THREADS-1)/THREADS, THREADS, 0, stream>>>(cnt, n4);

  // fused: build (first, XCD-affine) + layer-1 GEMM (fills in behind)
  k_build_gemm1<256,128><<<buildBlocks + gemmBlocks, THREADS, 0, stream>>>(
      ei, cnt, ssrc, E, M, feat, W1, h1h, buildBlocks);

  k_gather_l1<<<(M*64 + THREADS-1)/THREADS, THREADS, 0, stream>>>(cnt, ssrc, h1h, b1, o1h, M);

  k_gemm_mfma_f16a<128,64><<<gemmBlocks, THREADS, 0, stream>>>(o1h, W2, cnt, h2h, M);
  k_gather_l2<<<(M*64 + THREADS-1)/THREADS, THREADS, 0, stream>>>(cnt, ssrc, h2h, b2, out, M);
}